// Round 10
// baseline (586.807 us; speedup 1.0000x reference)
//
#include <hip/hip_runtime.h>
#include <cstdint>

#define D 128
#define P 8
#define L 3

typedef __attribute__((ext_vector_type(8))) _Float16 f16x8;
typedef __attribute__((ext_vector_type(4))) float    f32x4;
typedef __attribute__((ext_vector_type(2))) float    f32x2;

#if __has_builtin(__builtin_amdgcn_cvt_pk_f32_fp8) && __has_builtin(__builtin_amdgcn_cvt_pk_fp8_f32)
#define HAVE_FP8_CVT 1
#else
#define HAVE_FP8_CVT 0
#endif

// ---- fp8 e4m3fn -> f32 pair (OCP, gfx950). HI selects bytes 2,3 (imm operand).
template<bool HI>
static __device__ __forceinline__ f32x2 fp8_pair(uint32_t u) {
#if HAVE_FP8_CVT
    return __builtin_amdgcn_cvt_pk_f32_fp8((int)u, HI);
#else
    uint32_t w = HI ? (u >> 16) : u;
    f32x2 r;
#pragma unroll
    for (int i = 0; i < 2; i++) {
        uint32_t b = (w >> (8 * i)) & 0xffu;
        uint32_t mag = b & 0x7fu;
        uint16_t h = (uint16_t)(((b & 0x80u) << 8) | ((mag >= 8u) ? ((mag << 7) + 0x2000u) : 0u));
        union { uint16_t q; _Float16 hf; } c; c.q = h;
        r[i] = (float)c.hf;
    }
    return r;
#endif
}

static __device__ __forceinline__ uint32_t f32_to_fp8(float v) {
#if HAVE_FP8_CVT
    return (uint32_t)__builtin_amdgcn_cvt_pk_fp8_f32(v, v, 0, false) & 0xffu;
#else
    union { _Float16 hf; uint16_t q; } c; c.hf = (_Float16)v;
    uint32_t s = ((uint32_t)c.q >> 8) & 0x80u;
    int t = (int)(c.q & 0x7fff) - 0x2000;
    if (t < 0) return s;
    int r = (t + 63 + ((t >> 7) & 1)) >> 7;
    if (r > 0x7e) r = 0x7e;
    return s | (uint32_t)r;
#endif
}

// Merged prep: epk pack + row_ptr adjacent-diff + ww softmax-contraction.
__global__ void prep_all(const int* __restrict__ er, const int* __restrict__ col,
                         const float* __restrict__ vals,
                         const float* __restrict__ sp, const float* __restrict__ lw,
                         int* __restrict__ rp, uint32_t* __restrict__ epk,
                         _Float16* __restrict__ wwB, int n, int e) {
    int i = blockIdx.x * blockDim.x + threadIdx.x;
    if (i < e) {
        union { _Float16 h; uint16_t u; } v;
        v.h = (_Float16)vals[i];
        epk[i] = ((uint32_t)col[i] << 15) | (uint32_t)(v.u & 0x7FFFu);
        int cur = er[i];
        if (i == 0) {
            for (int r = 0; r <= cur; r++) rp[r] = 0;
        } else {
            int prev = er[i - 1];
            for (int r = prev + 1; r <= cur; r++) rp[r] = i;
        }
        if (i == e - 1) {
            for (int r = cur + 1; r <= n; r++) rp[r] = e;
        }
    }
    if (i < L * D * D) {
        int l = i / (D * D);
        int rem = i - l * D * D;
        int o = rem / D;
        int ii = rem - o * D;
        float wv[P];
        float m = -1e30f;
#pragma unroll
        for (int p = 0; p < P; p++) { wv[p] = lw[l * P + p]; m = fmaxf(m, wv[p]); }
        float s = 0.f;
#pragma unroll
        for (int p = 0; p < P; p++) { wv[p] = __expf(wv[p] - m); s += wv[p]; }
        float inv = 1.0f / s;
        const float* spp = sp + ((size_t)(l * D + o) * D + ii) * P;
        float acc = 0.f;
#pragma unroll
        for (int p = 0; p < P; p++) acc += spp[p] * wv[p];
        int kt = ii >> 5, kp = ii & 31;
        wwB[(((l * 4 + kt) * D + o) << 5) + kp] = (_Float16)(acc * inv);
    }
}

// MFMA on 16x128 tile, TWO waves: each wave does 4 col-tiles. fp8+scale output.
// srow: LDS[16] pre-zeroed by caller before its __syncthreads(). (r9-proven)
static __device__ __forceinline__ void mfma2w_q8(const _Float16 (*s_h)[136],
                                                 const _Float16* __restrict__ wwB_l,
                                                 uint8_t* __restrict__ y8,
                                                 float* __restrict__ scl,
                                                 unsigned* srow,
                                                 int row0, int n, int tid) {
    const int w = tid >> 6, lane = tid & 63;     // w in {0,1}
    const int quad = lane >> 4, l16 = lane & 15;
    f32x4 acc[4] = {};
#pragma unroll
    for (int kt = 0; kt < 4; kt++) {
        f16x8 af = *(const f16x8*)&s_h[l16][kt * 32 + quad * 8];
#pragma unroll
        for (int c = 0; c < 4; c++) {
            const int ct = w * 4 + c;
            f16x8 bf = *(const f16x8*)&wwB_l[((kt * D + ct * 16 + l16) << 5) + quad * 8];
            acc[c] = __builtin_amdgcn_mfma_f32_16x16x32_f16(af, bf, acc[c], 0, 0, 0);
        }
    }
    // C/D layout: col = lane&15, row = quad*4 + reg (m89-verified).
#pragma unroll
    for (int rg = 0; rg < 4; rg++) {
        float m = fmaxf(fmaxf(fabsf(acc[0][rg]), fabsf(acc[1][rg])),
                        fmaxf(fabsf(acc[2][rg]), fabsf(acc[3][rg])));
#pragma unroll
        for (int d = 1; d < 16; d <<= 1) m = fmaxf(m, __shfl_xor(m, d));
        if (l16 == 0) atomicMax(&srow[quad * 4 + rg], __float_as_uint(m));
    }
    __syncthreads();
#pragma unroll
    for (int rg = 0; rg < 4; rg++) {
        const int rr = quad * 4 + rg;
        const int row = row0 + rr;
        float rmax = fmaxf(__uint_as_float(srow[rr]), 1e-20f);
        float qs = 448.f / rmax;
        if (row < n) {
#pragma unroll
            for (int c = 0; c < 4; c++) {
                const int ct = w * 4 + c;
                float v = acc[c][rg] * qs;
                v = fminf(fmaxf(v, -448.f), 448.f);
                y8[row * D + ct * 16 + l16] = (uint8_t)f32_to_fp8(v);
            }
            if (w == 0 && l16 == 0) scl[row] = rmax * (1.f / 448.f);
        }
    }
}

// Y1 = cast_f16(x) * W0, quantized. 16-row tiles, 128 threads. (r9-proven)
__global__ __launch_bounds__(128, 8)
void gemm_x32(const float* __restrict__ x, const _Float16* __restrict__ wwB_l,
              uint8_t* __restrict__ y8, float* __restrict__ scl, int n) {
    __shared__ _Float16 s_h[16][136];
    __shared__ unsigned srow[16];
    const int tid = threadIdx.x;
    const int row0 = blockIdx.x * 16;
    const int sg = tid >> 4;
    const int c8 = (tid & 15) * 8;
    if (tid < 16) srow[tid] = 0;
#pragma unroll
    for (int h2 = 0; h2 < 2; h2++) {
        int rr = sg + h2 * 8;
        int row = row0 + rr;
        float4 v0 = {}, v1 = {};
        if (row < n) {
            v0 = *(const float4*)&x[row * D + c8];
            v1 = *(const float4*)&x[row * D + c8 + 4];
        }
        f16x8 h;
        h[0] = (_Float16)v0.x; h[1] = (_Float16)v0.y;
        h[2] = (_Float16)v0.z; h[3] = (_Float16)v0.w;
        h[4] = (_Float16)v1.x; h[5] = (_Float16)v1.y;
        h[6] = (_Float16)v1.z; h[7] = (_Float16)v1.w;
        *(f16x8*)&s_h[rr][c8] = h;
    }
    __syncthreads();
    mfma2w_q8(s_h, wwB_l, y8, scl, srow, row0, n, tid);
}

// ---------- column-sliced gather core (L2-resident slice per XCD) ----------
// 8 lanes per row x 4B (uint): one 32-col slice. Slice footprint = N*32B =
// 3.2 MB < 4 MB L2/XCD -> gathers become L2 hits after first touch.
// epk via nontemporal loads (no reuse within an XCD: row ranges are disjoint).
template<int NB>
static __device__ __forceinline__ void gslice_chunk(float (&a)[4],
        const uint8_t* __restrict__ y8, const uint32_t* __restrict__ epk,
        const float* __restrict__ scl, int e, int cb) {
    uint32_t m[NB];
#pragma unroll
    for (int j = 0; j < NB; j++) m[j] = __builtin_nontemporal_load(&epk[e + j]);
    uint32_t g[NB]; float sc[NB];
#pragma unroll
    for (int j = 0; j < NB; j++) {
        uint32_t row = m[j] >> 15;
        g[j]  = *(const uint32_t*)&y8[row * (uint32_t)D + (uint32_t)cb];
        sc[j] = scl[row];
    }
#pragma unroll
    for (int j = 0; j < NB; j++) {
        union { uint16_t u; _Float16 h; } vv; vv.u = (uint16_t)(m[j] & 0x7FFFu);
        float vf = (float)vv.h * sc[j];
        f32x2 p;
        p = fp8_pair<false>(g[j]); a[0] += vf * p[0]; a[1] += vf * p[1];
        p = fp8_pair<true >(g[j]); a[2] += vf * p[0]; a[3] += vf * p[1];
    }
}

static __device__ __forceinline__ void gslice_row(float (&a)[4],
        const uint8_t* __restrict__ y8, const uint32_t* __restrict__ epk,
        const float* __restrict__ scl, int e, int e1, int cb) {
    for (; e + 8 <= e1; e += 8) gslice_chunk<8>(a, y8, epk, scl, e, cb);
    if (e + 4 <= e1) { gslice_chunk<4>(a, y8, epk, scl, e, cb); e += 4; }
    for (; e < e1; e++) gslice_chunk<1>(a, y8, epk, scl, e, cb);
}

// AX = relu(adj * deq(Y)), fp16, for rows [rbeg, rend). Block = 32 rows x one
// 32-col slice; slice pinned to XCD pair via bid&7 (default round-robin map).
// No LDS, no barriers; NT stores keep the resident slice unevicted.
__global__ __launch_bounds__(128, 8)
void gather_ax(const uint8_t* __restrict__ y8, const float* __restrict__ scl,
               const int* __restrict__ rp, const uint32_t* __restrict__ epk,
               _Float16* __restrict__ ax, int rbeg, int rend, int nrb) {
    const int bid = blockIdx.x;
    const int xcd = bid & 7;
    const int slice = xcd >> 1;
    const int rb = (bid >> 3) * 2 + (xcd & 1);
    if (rb >= nrb) return;
    const int tid = threadIdx.x;
    const int sg = tid >> 3, l8 = tid & 7;
    const int cb = slice * 32 + l8 * 4;
    const int r0 = rbeg + rb * 32 + sg * 2;
#pragma unroll 1
    for (int q = 0; q < 2; q++) {
        const int r = r0 + q;
        if (r >= rend) continue;
        float a[4] = {0.f, 0.f, 0.f, 0.f};
        gslice_row(a, y8, epk, scl, rp[r], rp[r + 1], cb);
        union { _Float16 h[4]; unsigned long long u; } o;
#pragma unroll
        for (int k = 0; k < 4; k++) o.h[k] = (_Float16)fmaxf(a[k], 0.f);
        __builtin_nontemporal_store(o.u,
            (unsigned long long*)&ax[(size_t)(r - rbeg) * D + cb]);
    }
}

// Final layer: out = adj * deq(Y3), fp32, sliced directly (no relu, no quant).
__global__ __launch_bounds__(128, 8)
void gather_out(const uint8_t* __restrict__ y8, const float* __restrict__ scl,
                const int* __restrict__ rp, const uint32_t* __restrict__ epk,
                float* __restrict__ out, int n, int nrb) {
    const int bid = blockIdx.x;
    const int xcd = bid & 7;
    const int slice = xcd >> 1;
    const int rb = (bid >> 3) * 2 + (xcd & 1);
    if (rb >= nrb) return;
    const int tid = threadIdx.x;
    const int sg = tid >> 3, l8 = tid & 7;
    const int cb = slice * 32 + l8 * 4;
    const int r0 = rb * 32 + sg * 2;
#pragma unroll 1
    for (int q = 0; q < 2; q++) {
        const int r = r0 + q;
        if (r >= n) continue;
        float a[4] = {0.f, 0.f, 0.f, 0.f};
        gslice_row(a, y8, epk, scl, rp[r], rp[r + 1], cb);
        unsigned long long* op = (unsigned long long*)&out[(size_t)r * D + cb];
        union { float f[2]; unsigned long long u; } w;
        w.f[0] = a[0]; w.f[1] = a[1]; __builtin_nontemporal_store(w.u, op);
        w.f[0] = a[2]; w.f[1] = a[3]; __builtin_nontemporal_store(w.u, op + 1);
    }
}

// Dense: Y_next = q8(AX * W). AX fp16 rows [rbeg, rend), offset-indexed.
__global__ __launch_bounds__(128, 8)
void dense_q8(const _Float16* __restrict__ ax, const _Float16* __restrict__ wwB_l,
              uint8_t* __restrict__ y8o, float* __restrict__ sclo,
              int rbeg, int rend) {
    __shared__ _Float16 s_h[16][136];
    __shared__ unsigned srow[16];
    const int tid = threadIdx.x;
    const int row0 = rbeg + blockIdx.x * 16;
    const int sg = tid >> 4;
    const int c8 = (tid & 15) * 8;
    if (tid < 16) srow[tid] = 0;
#pragma unroll
    for (int h2 = 0; h2 < 2; h2++) {
        int rr = sg + h2 * 8;
        int row = row0 + rr;
        f16x8 h = {0, 0, 0, 0, 0, 0, 0, 0};
        if (row < rend) h = *(const f16x8*)&ax[(size_t)(row - rbeg) * D + c8];
        *(f16x8*)&s_h[rr][c8] = h;
    }
    __syncthreads();
    mfma2w_q8(s_h, wwB_l, y8o, sclo, srow, row0, rend, tid);
}

extern "C" void kernel_launch(void* const* d_in, const int* in_sizes, int n_in,
                              void* d_out, int out_size, void* d_ws, size_t ws_size,
                              hipStream_t stream) {
    const int*   edge_row  = (const int*)d_in[0];
    const int*   edge_col  = (const int*)d_in[1];
    const float* edge_vals = (const float*)d_in[2];
    const float* x         = (const float*)d_in[3];
    const float* sp        = (const float*)d_in[4];
    const float* lw        = (const float*)d_in[5];
    float* out = (float*)d_out;

    const int E_ = in_sizes[0];
    const int N_ = in_sizes[3] / D;

    // Workspace: row_ptr | epk | wwB | y8A | y8B | scA | scB | AX(half) ~46 MB
    char* ws = (char*)d_ws;
    int* row_ptr = (int*)ws;
    size_t off = (((size_t)(N_ + 1) * sizeof(int)) + 255) & ~(size_t)255;
    uint32_t* epk = (uint32_t*)(ws + off);
    off += (size_t)E_ * sizeof(uint32_t);
    off = (off + 255) & ~(size_t)255;
    _Float16* wwB = (_Float16*)(ws + off);
    off += (size_t)L * 4 * D * 32 * sizeof(_Float16);
    off = (off + 255) & ~(size_t)255;
    uint8_t* y8A = (uint8_t*)(ws + off);
    off += (size_t)N_ * D;
    uint8_t* y8B = (uint8_t*)(ws + off);
    off += (size_t)N_ * D;
    off = (off + 255) & ~(size_t)255;
    float* scA = (float*)(ws + off);
    off += (size_t)N_ * sizeof(float);
    float* scB = (float*)(ws + off);
    off += (size_t)N_ * sizeof(float);
    off = (off + 255) & ~(size_t)255;
    _Float16* axb = (_Float16*)(ws + off);   // holds max(Nh, N-Nh) rows

    const int pgrid = (E_ > L * D * D ? E_ : L * D * D);
    prep_all<<<(pgrid + 255) / 256, 256, 0, stream>>>(edge_row, edge_col, edge_vals,
                                                      sp, lw, row_ptr, epk, wwB, N_, E_);

    const int WWL = 4 * D * 32;
    const int Nh0 = ((N_ + 63) / 64) * 32;           // split point, multiple of 32
    const int Nh = Nh0 < N_ ? Nh0 : N_;

    // Y1 = x*W0
    gemm_x32<<<(N_ + 15) / 16, 128, 0, stream>>>(x, wwB, y8A, scA, N_);

    // Two fused layers, each = (gather_ax + dense_q8) over two row-halves.
    struct Seg { int b, e; };
    Seg segs[2] = { {0, Nh}, {Nh, N_} };
    const uint8_t* yin[2] = { y8A, y8B };
    const float*   sin[2] = { scA, scB };
    uint8_t* yout[2] = { y8B, y8A };
    float*   sout[2] = { scB, scA };
    for (int l = 0; l < 2; l++) {
        for (int h = 0; h < 2; h++) {
            const int rb0 = segs[h].b, rb1 = segs[h].e;
            const int nrows = rb1 - rb0;
            if (nrows <= 0) continue;
            const int nrb = (nrows + 31) / 32;
            const int grid = ((nrb + 1) / 2) * 8;
            gather_ax<<<grid, 128, 0, stream>>>(yin[l], sin[l], row_ptr, epk,
                                                axb, rb0, rb1, nrb);
            dense_q8<<<(nrows + 15) / 16, 128, 0, stream>>>(axb, wwB + (l + 1) * WWL,
                                                            yout[l], sout[l], rb0, rb1);
        }
    }

    // out = adj * Y3 (Y3 in y8A after layer 2)
    const int nrbF = (N_ + 31) / 32;
    const int gridF = ((nrbF + 1) / 2) * 8;
    gather_out<<<gridF, 128, 0, stream>>>(y8A, scA, row_ptr, epk, out, N_, nrbF);
}